// Round 10
// baseline (160.082 us; speedup 1.0000x reference)
//
#include <hip/hip_runtime.h>
#include <hip/hip_bf16.h>

#define NB 4
#define CC 384
#define HEADS 8
#define HD 48
#define NN 16384          // H*W
#define NROWS (NB*CC)     // 1536

typedef __attribute__((ext_vector_type(8))) short bf16x8;
typedef __attribute__((ext_vector_type(4))) float f32x4;

__device__ __forceinline__ unsigned short f2bf(float f) {
  __hip_bfloat16 h = __float2bfloat16(f);
  return __builtin_bit_cast(unsigned short, h);
}
__device__ __forceinline__ unsigned int packbf(float a, float b) {
  return (unsigned int)f2bf(a) | ((unsigned int)f2bf(b) << 16);
}
__device__ __forceinline__ float bf2f(short s) {
  unsigned int u = ((unsigned int)(unsigned short)s) << 16;
  return __builtin_bit_cast(float, u);
}

// ---------------- K1: pure flat convert-copy (no reductions at all) ---------
// grid (1024, 2): y selects tensor; x grid-strides. 2 float4 loads -> 1 uint4
// packed-bf16 store per iter. Maximally copy-shaped (m13 pattern).
__global__ __launch_bounds__(256) void k_copy(
    const float* __restrict__ in1, const float* __restrict__ in2,
    unsigned short* __restrict__ qbf, unsigned short* __restrict__ kbf)
{
  const float4* src = (const float4*)(blockIdx.y ? in2 : in1);
  uint4* dst = (uint4*)(blockIdx.y ? kbf : qbf);
  const int n = NROWS * NN / 8;            // 3,145,728 uint4 outputs
  int stride = gridDim.x * 256;
  for (int i = blockIdx.x * 256 + threadIdx.x; i < n; i += stride) {
    float4 v0 = src[2*i], v1 = src[2*i+1];
    uint4 o;
    o.x = packbf(v0.x, v0.y); o.y = packbf(v0.z, v0.w);
    o.z = packbf(v1.x, v1.y); o.w = packbf(v1.z, v1.w);
    dst[i] = o;
  }
}

// ---------------- K2: raw Gram + fused row-sumsq, split-K partials ----------
__global__ __launch_bounds__(256) void k_gram(
    const unsigned short* __restrict__ qbf, const unsigned short* __restrict__ kbf,
    float* __restrict__ partial, float* __restrict__ sumsq_part)
{
  int bh = blockIdx.x;     // 32
  int chunk = blockIdx.y;  // 16
  int wave = threadIdx.x >> 6, lane = threadIdx.x & 63;
  int b = bh >> 3, h = bh & 7;
  size_t base = ((size_t)(b*CC + h*HD)) * NN;
  int lrow = lane & 15, lk = (lane >> 4) << 3;
  int kstart = chunk*1024 + wave*256;
  f32x4 acc[3][3] = {};
  float sq[3] = {0.f,0.f,0.f}, sk[3] = {0.f,0.f,0.f};
  for (int ks = 0; ks < 8; ++ks) {
    int kpos = kstart + ks*32 + lk;
    bf16x8 a[3], bb[3];
    #pragma unroll
    for (int t = 0; t < 3; ++t) {
      int rr = t*16 + lrow;
      a[t]  = *(const bf16x8*)(qbf + base + (size_t)rr * NN + kpos);
      bb[t] = *(const bf16x8*)(kbf + base + (size_t)rr * NN + kpos);
    }
    #pragma unroll
    for (int t = 0; t < 3; ++t) {
      #pragma unroll
      for (int j = 0; j < 8; ++j) {
        float fa = bf2f(a[t][j]);  sq[t] += fa*fa;
        float fb = bf2f(bb[t][j]); sk[t] += fb*fb;
      }
    }
    #pragma unroll
    for (int i = 0; i < 3; ++i)
      #pragma unroll
      for (int j = 0; j < 3; ++j)
        acc[i][j] = __builtin_amdgcn_mfma_f32_16x16x32_bf16(a[i], bb[j], acc[i][j], 0, 0, 0);
  }
  __shared__ float red[4][HD][HD+1];
  __shared__ float sqs[4][96];
  #pragma unroll
  for (int t = 0; t < 3; ++t) {
    float s = sq[t]; s += __shfl_xor(s, 16); s += __shfl_xor(s, 32);
    if (lane < 16) sqs[wave][t*16 + lane] = s;
    float s2 = sk[t]; s2 += __shfl_xor(s2, 16); s2 += __shfl_xor(s2, 32);
    if (lane < 16) sqs[wave][48 + t*16 + lane] = s2;
  }
  #pragma unroll
  for (int i = 0; i < 3; ++i)
    #pragma unroll
    for (int j = 0; j < 3; ++j)
      #pragma unroll
      for (int m = 0; m < 4; ++m) {
        int rr = i*16 + (lane>>4)*4 + m;
        int cc2 = j*16 + (lane&15);
        red[wave][rr][cc2] = acc[i][j][m];
      }
  __syncthreads();
  float* pout = partial + ((size_t)bh*16 + chunk) * (HD*HD);
  for (int e = threadIdx.x; e < HD*HD; e += 256) {
    int r = e / HD, c = e % HD;
    pout[e] = red[0][r][c] + red[1][r][c] + red[2][r][c] + red[3][r][c];
  }
  if (threadIdx.x < 96) {
    float* sout = sumsq_part + ((size_t)bh*16 + chunk) * 96;
    sout[threadIdx.x] = sqs[0][threadIdx.x] + sqs[1][threadIdx.x]
                      + sqs[2][threadIdx.x] + sqs[3][threadIdx.x];
  }
}

// ---------------- K3a: reduce partials+sumsq -> rinv, softmax ---------------
__global__ __launch_bounds__(256) void k_redsm(
    const float* __restrict__ partial, const float* __restrict__ sumsq_part,
    const float* __restrict__ temp, float* __restrict__ attn_out,
    float* __restrict__ rinv_k_g)
{
  int bh = blockIdx.x; int b = bh >> 3, h = bh & 7;
  __shared__ float attn[HD][HD+1];
  __shared__ float rqs[HD], rks[HD];
  if (threadIdx.x < 96) {
    float s = 0.f;
    #pragma unroll
    for (int c = 0; c < 16; ++c)
      s += sumsq_part[((size_t)bh*16 + c)*96 + threadIdx.x];
    float rinv = 1.f / fmaxf(sqrtf(s), 1e-12f);
    if (threadIdx.x < 48) rqs[threadIdx.x] = rinv;
    else { rks[threadIdx.x-48] = rinv; rinv_k_g[b*CC + h*HD + threadIdx.x-48] = rinv; }
  }
  const float* p = partial + (size_t)bh * 16 * (HD*HD);
  float tscale = temp[h];
  __syncthreads();
  for (int e = threadIdx.x; e < HD*HD; e += 256) {
    float s = 0.f;
    #pragma unroll
    for (int c2 = 0; c2 < 16; ++c2) s += p[c2*(HD*HD) + e];
    attn[e/HD][e%HD] = s * tscale * rqs[e/HD] * rks[e%HD];
  }
  __syncthreads();
  if (threadIdx.x < HD) {
    float* rowp = attn[threadIdx.x];
    float m = rowp[0];
    for (int j = 1; j < HD; ++j) m = fmaxf(m, rowp[j]);
    float sum = 0.f;
    for (int j = 0; j < HD; ++j) { float e = expf(rowp[j]-m); rowp[j] = e; sum += e; }
    float inv = 1.f / sum;
    for (int j = 0; j < HD; ++j) rowp[j] *= inv;
  }
  __syncthreads();
  float* ao = attn_out + (size_t)bh * (HD*HD);
  for (int e = threadIdx.x; e < HD*HD; e += 256)
    ao[e] = attn[e/HD][e%HD];
}

// ---------------- K3b: M = (projW_h @ attn_h) * rinv_k[col], bf16 ----------
__global__ __launch_bounds__(256) void k_m(
    const float* __restrict__ attn, const float* __restrict__ proj_w,
    const float* __restrict__ rinv_k, unsigned short* __restrict__ Mbf)
{
  int b = blockIdx.x, ot = blockIdx.y;  // grid (4, 24)
  int o0 = ot * 16;
  __shared__ float sw[16*CC];           // 24.6 KB
  __shared__ float sa[HEADS*HD*HD];     // 73.7 KB
  const float* ab = attn + (size_t)b * HEADS * HD * HD;
  for (int i = threadIdx.x; i < HEADS*HD*HD; i += 256) sa[i] = ab[i];
  for (int i = threadIdx.x; i < 16*CC; i += 256)
    sw[i] = proj_w[(size_t)(o0 + i/CC)*CC + (i%CC)];
  __syncthreads();
  for (int idx = threadIdx.x; idx < 16*96; idx += 256) {
    int o = idx / 96, c4 = idx % 96;
    int col = c4 * 4;
    int h = col / HD, d = col % HD;
    const float* wp = sw + o*CC + h*HD;
    const float* ap = sa + h*HD*HD + d;
    f32x4 s = {0.f, 0.f, 0.f, 0.f};
    #pragma unroll
    for (int c2 = 0; c2 < HD; ++c2) {
      float w = wp[c2];
      f32x4 av = *(const f32x4*)(ap + c2*HD);
      s += w * av;
    }
    f32x4 rk = *(const f32x4*)(rinv_k + b*CC + col);
    s *= rk;
    ushort4 o4;
    o4.x = f2bf(s[0]); o4.y = f2bf(s[1]); o4.z = f2bf(s[2]); o4.w = f2bf(s[3]);
    *(ushort4*)(Mbf + ((size_t)b*CC + o0 + o)*CC + col) = o4;
  }
}

// ---------------- K5: out = M @ k0 + bias  (384x16384x384 per batch) --------
#define BM 128
#define BN 128
#define BK 64

__global__ __launch_bounds__(256) void k_final(
    const unsigned short* __restrict__ kbf, const unsigned short* __restrict__ Mbf,
    const float* __restrict__ bias, float* __restrict__ out)
{
  int b = blockIdx.z;
  int bm = blockIdx.y * BM, bn = blockIdx.x * BN;
  int tid = threadIdx.x, lane = tid & 63, wave = tid >> 6;
  int wrow = wave >> 1, wcol = wave & 1;
  __shared__ unsigned short Bt[BN * BK];   // transposed+swizzled [n][k], 16 KB
  char* btb = (char*)Bt;
  const unsigned short* kb = kbf + (size_t)b * CC * NN;
  const unsigned short* Mb = Mbf + (size_t)b * CC * CC;
  f32x4 acc[4][4] = {};
  int lrow = lane & 15, lkg = lane >> 4;
  for (int k0 = 0; k0 < CC; k0 += BK) {
    #pragma unroll
    for (int s = 0; s < 2; ++s) {
      int slot = tid + s*256;
      int cp = slot >> 4;        // dword column (pair of k/channel rows), 0..31
      int ng = slot & 15;        // group of 8 n-columns
      int n0 = ng * 8;
      int c = k0 + cp*2;
      union { uint4 q; unsigned short u[8]; } r0, r1;
      r0.q = *(const uint4*)(kb + (size_t)c*NN + bn + n0);
      r1.q = *(const uint4*)(kb + (size_t)(c+1)*NN + bn + n0);
      #pragma unroll
      for (int i = 0; i < 8; ++i) {
        int n = n0 + i;
        unsigned int val = (unsigned int)r0.u[i] | ((unsigned int)r1.u[i] << 16);
        int pc = (cp>>2) ^ (n & 7) ^ ((n >> 3) & 7);
        *(unsigned int*)(btb + n*128 + (pc<<4) + ((cp&3)<<2)) = val;
      }
    }
    __syncthreads();
    #pragma unroll
    for (int kk = 0; kk < BK; kk += 32) {
      bf16x8 af[4], bfr[4];
      #pragma unroll
      for (int t = 0; t < 4; ++t) {
        int o = bm + wrow*64 + t*16 + lrow;
        af[t] = *(const bf16x8*)(Mb + (size_t)o*CC + (k0 + kk + (lkg<<3)));
        int n = wcol*64 + t*16 + lrow;
        int lc = (kk>>3) + lkg;
        int pc = lc ^ (n & 7) ^ ((n >> 3) & 7);
        bfr[t] = *(const bf16x8*)(btb + n*128 + (pc<<4));
      }
      #pragma unroll
      for (int i = 0; i < 4; ++i)
        #pragma unroll
        for (int j = 0; j < 4; ++j)
          acc[i][j] = __builtin_amdgcn_mfma_f32_16x16x32_bf16(af[i], bfr[j], acc[i][j], 0, 0, 0);
    }
    __syncthreads();
  }
  #pragma unroll
  for (int i = 0; i < 4; ++i) {
    int obase = bm + wrow*64 + i*16 + lkg*4;
    #pragma unroll
    for (int j = 0; j < 4; ++j) {
      int n = bn + wcol*64 + j*16 + lrow;
      #pragma unroll
      for (int m = 0; m < 4; ++m) {
        int o = obase + m;
        out[((size_t)b*CC + o)*NN + n] = acc[i][j][m] + bias[o];
      }
    }
  }
}

extern "C" void kernel_launch(void* const* d_in, const int* in_sizes, int n_in,
                              void* d_out, int out_size, void* d_ws, size_t ws_size,
                              hipStream_t stream)
{
  const float* in1    = (const float*)d_in[0];
  const float* in2    = (const float*)d_in[1];
  const float* temp   = (const float*)d_in[2];
  const float* proj_w = (const float*)d_in[3];
  const float* proj_b = (const float*)d_in[4];
  float* out = (float*)d_out;
  char* ws = (char*)d_ws;

  size_t off = 0;
  unsigned short* qbf = (unsigned short*)(ws + off); off += (size_t)NROWS*NN*2;   // 50331648
  unsigned short* kbf = (unsigned short*)(ws + off); off += (size_t)NROWS*NN*2;   // 50331648
  float* partial    = (float*)(ws + off); off += (size_t)32*16*HD*HD*4;           // 4718592
  float* sumsq_part = (float*)(ws + off); off += (size_t)32*16*96*4;              // 196608
  float* attn_out   = (float*)(ws + off); off += (size_t)32*HD*HD*4;              // 294912
  float* rinv_k     = (float*)(ws + off); off += NROWS*4;                         // 6144
  unsigned short* Mbf = (unsigned short*)(ws + off);                              // 1179648

  k_copy<<<dim3(1024, 2), dim3(256), 0, stream>>>(in1, in2, qbf, kbf);
  k_gram<<<dim3(32, 16), dim3(256), 0, stream>>>(qbf, kbf, partial, sumsq_part);
  k_redsm<<<dim3(32), dim3(256), 0, stream>>>(partial, sumsq_part, temp, attn_out, rinv_k);
  k_m<<<dim3(NB, 24), dim3(256), 0, stream>>>(attn_out, proj_w, rinv_k, Mbf);
  k_final<<<dim3(NN/BN, CC/BM, NB), dim3(256), 0, stream>>>(kbf, Mbf, proj_b, out);
}

// Round 11
// 142.820 us; speedup vs baseline: 1.1209x; 1.1209x over previous
//
#include <hip/hip_runtime.h>
#include <hip/hip_bf16.h>

#define NB 4
#define CC 384
#define HEADS 8
#define HD 48
#define NN 16384          // H*W
#define NROWS (NB*CC)     // 1536

typedef __attribute__((ext_vector_type(8))) short bf16x8;
typedef __attribute__((ext_vector_type(4))) float f32x4;

__device__ __forceinline__ unsigned short f2bf(float f) {
  __hip_bfloat16 h = __float2bfloat16(f);
  return __builtin_bit_cast(unsigned short, h);
}
__device__ __forceinline__ unsigned int packbf(float a, float b) {
  return (unsigned int)f2bf(a) | ((unsigned int)f2bf(b) << 16);
}

// ---------------- K2: Gram from fp32 inputs (inline bf16 cvt) + fused sumsq -
// grid (32 bh, 32 chunks); each chunk covers 512 k-positions.
__global__ __launch_bounds__(256) void k_gram(
    const float* __restrict__ in1, const float* __restrict__ in2,
    float* __restrict__ partial, float* __restrict__ sumsq_part)
{
  int bh = blockIdx.x;     // 32
  int chunk = blockIdx.y;  // 32
  int wave = threadIdx.x >> 6, lane = threadIdx.x & 63;
  int b = bh >> 3, h = bh & 7;
  size_t base = ((size_t)(b*CC + h*HD)) * NN;
  int lrow = lane & 15, lk = (lane >> 4) << 3;
  int kstart = chunk*512 + wave*128;
  f32x4 acc[3][3] = {};
  float sq[3] = {0.f,0.f,0.f}, sk[3] = {0.f,0.f,0.f};
  for (int ks = 0; ks < 4; ++ks) {
    int kpos = kstart + ks*32 + lk;
    bf16x8 a[3], bb[3];
    #pragma unroll
    for (int t = 0; t < 3; ++t) {
      int rr = t*16 + lrow;
      const float* pq = in1 + base + (size_t)rr * NN + kpos;
      const float* pk = in2 + base + (size_t)rr * NN + kpos;
      float4 q0 = *(const float4*)pq, q1 = *((const float4*)pq + 1);
      float4 k0 = *(const float4*)pk, k1 = *((const float4*)pk + 1);
      union { bf16x8 v; unsigned short u[8]; } ua, ub;
      ua.u[0]=f2bf(q0.x); ua.u[1]=f2bf(q0.y); ua.u[2]=f2bf(q0.z); ua.u[3]=f2bf(q0.w);
      ua.u[4]=f2bf(q1.x); ua.u[5]=f2bf(q1.y); ua.u[6]=f2bf(q1.z); ua.u[7]=f2bf(q1.w);
      ub.u[0]=f2bf(k0.x); ub.u[1]=f2bf(k0.y); ub.u[2]=f2bf(k0.z); ub.u[3]=f2bf(k0.w);
      ub.u[4]=f2bf(k1.x); ub.u[5]=f2bf(k1.y); ub.u[6]=f2bf(k1.z); ub.u[7]=f2bf(k1.w);
      a[t] = ua.v; bb[t] = ub.v;
      sq[t] += q0.x*q0.x + q0.y*q0.y + q0.z*q0.z + q0.w*q0.w
             + q1.x*q1.x + q1.y*q1.y + q1.z*q1.z + q1.w*q1.w;
      sk[t] += k0.x*k0.x + k0.y*k0.y + k0.z*k0.z + k0.w*k0.w
             + k1.x*k1.x + k1.y*k1.y + k1.z*k1.z + k1.w*k1.w;
    }
    #pragma unroll
    for (int i = 0; i < 3; ++i)
      #pragma unroll
      for (int j = 0; j < 3; ++j)
        acc[i][j] = __builtin_amdgcn_mfma_f32_16x16x32_bf16(a[i], bb[j], acc[i][j], 0, 0, 0);
  }
  __shared__ float red[4][HD][HD+1];
  __shared__ float sqs[4][96];
  #pragma unroll
  for (int t = 0; t < 3; ++t) {
    float s = sq[t]; s += __shfl_xor(s, 16); s += __shfl_xor(s, 32);
    if (lane < 16) sqs[wave][t*16 + lane] = s;
    float s2 = sk[t]; s2 += __shfl_xor(s2, 16); s2 += __shfl_xor(s2, 32);
    if (lane < 16) sqs[wave][48 + t*16 + lane] = s2;
  }
  #pragma unroll
  for (int i = 0; i < 3; ++i)
    #pragma unroll
    for (int j = 0; j < 3; ++j)
      #pragma unroll
      for (int m = 0; m < 4; ++m) {
        int rr = i*16 + (lane>>4)*4 + m;
        int cc2 = j*16 + (lane&15);
        red[wave][rr][cc2] = acc[i][j][m];
      }
  __syncthreads();
  float* pout = partial + ((size_t)bh*32 + chunk) * (HD*HD);
  for (int e = threadIdx.x; e < HD*HD; e += 256) {
    int r = e / HD, c = e % HD;
    pout[e] = red[0][r][c] + red[1][r][c] + red[2][r][c] + red[3][r][c];
  }
  if (threadIdx.x < 96) {
    float* sout = sumsq_part + ((size_t)bh*32 + chunk) * 96;
    sout[threadIdx.x] = sqs[0][threadIdx.x] + sqs[1][threadIdx.x]
                      + sqs[2][threadIdx.x] + sqs[3][threadIdx.x];
  }
}

// ---------------- K3a: reduce partials+sumsq -> rinv, softmax ---------------
__global__ __launch_bounds__(256) void k_redsm(
    const float* __restrict__ partial, const float* __restrict__ sumsq_part,
    const float* __restrict__ temp, float* __restrict__ attn_out,
    float* __restrict__ rinv_k_g)
{
  int bh = blockIdx.x; int b = bh >> 3, h = bh & 7;
  __shared__ float attn[HD][HD+1];
  __shared__ float rqs[HD], rks[HD];
  if (threadIdx.x < 96) {
    float s = 0.f;
    #pragma unroll
    for (int c = 0; c < 32; ++c)
      s += sumsq_part[((size_t)bh*32 + c)*96 + threadIdx.x];
    float rinv = 1.f / fmaxf(sqrtf(s), 1e-12f);
    if (threadIdx.x < 48) rqs[threadIdx.x] = rinv;
    else { rks[threadIdx.x-48] = rinv; rinv_k_g[b*CC + h*HD + threadIdx.x-48] = rinv; }
  }
  const float* p = partial + (size_t)bh * 32 * (HD*HD);
  float tscale = temp[h];
  __syncthreads();
  for (int e = threadIdx.x; e < HD*HD; e += 256) {
    float s = 0.f;
    #pragma unroll
    for (int c2 = 0; c2 < 32; ++c2) s += p[c2*(HD*HD) + e];
    attn[e/HD][e%HD] = s * tscale * rqs[e/HD] * rks[e%HD];
  }
  __syncthreads();
  if (threadIdx.x < HD) {
    float* rowp = attn[threadIdx.x];
    float m = rowp[0];
    for (int j = 1; j < HD; ++j) m = fmaxf(m, rowp[j]);
    float sum = 0.f;
    for (int j = 0; j < HD; ++j) { float e = expf(rowp[j]-m); rowp[j] = e; sum += e; }
    float inv = 1.f / sum;
    for (int j = 0; j < HD; ++j) rowp[j] *= inv;
  }
  __syncthreads();
  float* ao = attn_out + (size_t)bh * (HD*HD);
  for (int e = threadIdx.x; e < HD*HD; e += 256)
    ao[e] = attn[e/HD][e%HD];
}

// ---------------- K3b: M = (projW_h @ attn_h) * rinv_k[col], bf16 ----------
__global__ __launch_bounds__(256) void k_m(
    const float* __restrict__ attn, const float* __restrict__ proj_w,
    const float* __restrict__ rinv_k, unsigned short* __restrict__ Mbf)
{
  int b = blockIdx.x, ot = blockIdx.y;  // grid (4, 24)
  int o0 = ot * 16;
  __shared__ float sw[16*CC];           // 24.6 KB
  __shared__ float sa[HEADS*HD*HD];     // 73.7 KB
  const float* ab = attn + (size_t)b * HEADS * HD * HD;
  for (int i = threadIdx.x; i < HEADS*HD*HD; i += 256) sa[i] = ab[i];
  for (int i = threadIdx.x; i < 16*CC; i += 256)
    sw[i] = proj_w[(size_t)(o0 + i/CC)*CC + (i%CC)];
  __syncthreads();
  for (int idx = threadIdx.x; idx < 16*96; idx += 256) {
    int o = idx / 96, c4 = idx % 96;
    int col = c4 * 4;
    int h = col / HD, d = col % HD;
    const float* wp = sw + o*CC + h*HD;
    const float* ap = sa + h*HD*HD + d;
    f32x4 s = {0.f, 0.f, 0.f, 0.f};
    #pragma unroll
    for (int c2 = 0; c2 < HD; ++c2) {
      float w = wp[c2];
      f32x4 av = *(const f32x4*)(ap + c2*HD);
      s += w * av;
    }
    f32x4 rk = *(const f32x4*)(rinv_k + b*CC + col);
    s *= rk;
    ushort4 o4;
    o4.x = f2bf(s[0]); o4.y = f2bf(s[1]); o4.z = f2bf(s[2]); o4.w = f2bf(s[3]);
    *(ushort4*)(Mbf + ((size_t)b*CC + o0 + o)*CC + col) = o4;
  }
}

// ---------------- K5: out = M @ bf16(in2) + bias, B staged from fp32 --------
#define BM 128
#define BN 128
#define BK 64

__global__ __launch_bounds__(256) void k_final(
    const float* __restrict__ in2, const unsigned short* __restrict__ Mbf,
    const float* __restrict__ bias, float* __restrict__ out)
{
  int b = blockIdx.z;
  int bm = blockIdx.y * BM, bn = blockIdx.x * BN;
  int tid = threadIdx.x, lane = tid & 63, wave = tid >> 6;
  int wrow = wave >> 1, wcol = wave & 1;
  __shared__ unsigned short Bt[BN * BK];   // transposed+swizzled [n][k], 16 KB
  char* btb = (char*)Bt;
  const float* kb = in2 + (size_t)b * CC * NN;
  const unsigned short* Mb = Mbf + (size_t)b * CC * CC;
  f32x4 acc[4][4] = {};
  int lrow = lane & 15, lkg = lane >> 4;
  for (int k0 = 0; k0 < CC; k0 += BK) {
    // stage B tile (BK ch-rows x BN cols) from fp32, cvt->bf16, transposed+swizzled
    #pragma unroll
    for (int s = 0; s < 2; ++s) {
      int slot = tid + s*256;
      int cp = slot >> 4;        // pair of channel rows, 0..31
      int ng = slot & 15;        // group of 8 n-columns
      int n0 = ng * 8;
      int c = k0 + cp*2;
      const float* p0 = kb + (size_t)c*NN + bn + n0;
      const float* p1 = kb + (size_t)(c+1)*NN + bn + n0;
      float4 a0 = *(const float4*)p0, a1 = *((const float4*)p0 + 1);
      float4 b0 = *(const float4*)p1, b1 = *((const float4*)p1 + 1);
      float lo[8] = {a0.x,a0.y,a0.z,a0.w,a1.x,a1.y,a1.z,a1.w};
      float hi[8] = {b0.x,b0.y,b0.z,b0.w,b1.x,b1.y,b1.z,b1.w};
      #pragma unroll
      for (int i = 0; i < 8; ++i) {
        int n = n0 + i;
        unsigned int val = packbf(lo[i], hi[i]);
        int pc = (cp>>2) ^ (n & 7) ^ ((n >> 3) & 7);
        *(unsigned int*)(btb + n*128 + (pc<<4) + ((cp&3)<<2)) = val;
      }
    }
    __syncthreads();
    #pragma unroll
    for (int kk = 0; kk < BK; kk += 32) {
      bf16x8 af[4], bfr[4];
      #pragma unroll
      for (int t = 0; t < 4; ++t) {
        int o = bm + wrow*64 + t*16 + lrow;
        af[t] = *(const bf16x8*)(Mb + (size_t)o*CC + (k0 + kk + (lkg<<3)));
        int n = wcol*64 + t*16 + lrow;
        int lc = (kk>>3) + lkg;
        int pc = lc ^ (n & 7) ^ ((n >> 3) & 7);
        bfr[t] = *(const bf16x8*)(btb + n*128 + (pc<<4));
      }
      #pragma unroll
      for (int i = 0; i < 4; ++i)
        #pragma unroll
        for (int j = 0; j < 4; ++j)
          acc[i][j] = __builtin_amdgcn_mfma_f32_16x16x32_bf16(af[i], bfr[j], acc[i][j], 0, 0, 0);
    }
    __syncthreads();
  }
  #pragma unroll
  for (int i = 0; i < 4; ++i) {
    int obase = bm + wrow*64 + i*16 + lkg*4;
    #pragma unroll
    for (int j = 0; j < 4; ++j) {
      int n = bn + wcol*64 + j*16 + lrow;
      #pragma unroll
      for (int m = 0; m < 4; ++m) {
        int o = obase + m;
        out[((size_t)b*CC + o)*NN + n] = acc[i][j][m] + bias[o];
      }
    }
  }
}

extern "C" void kernel_launch(void* const* d_in, const int* in_sizes, int n_in,
                              void* d_out, int out_size, void* d_ws, size_t ws_size,
                              hipStream_t stream)
{
  const float* in1    = (const float*)d_in[0];
  const float* in2    = (const float*)d_in[1];
  const float* temp   = (const float*)d_in[2];
  const float* proj_w = (const float*)d_in[3];
  const float* proj_b = (const float*)d_in[4];
  float* out = (float*)d_out;
  char* ws = (char*)d_ws;

  size_t off = 0;
  float* partial    = (float*)(ws + off); off += (size_t)32*32*HD*HD*4;           // 9437184
  float* sumsq_part = (float*)(ws + off); off += (size_t)32*32*96*4;              // 393216
  float* attn_out   = (float*)(ws + off); off += (size_t)32*HD*HD*4;              // 294912
  float* rinv_k     = (float*)(ws + off); off += NROWS*4;                         // 6144
  unsigned short* Mbf = (unsigned short*)(ws + off);                              // 1179648

  k_gram<<<dim3(32, 32), dim3(256), 0, stream>>>(in1, in2, partial, sumsq_part);
  k_redsm<<<dim3(32), dim3(256), 0, stream>>>(partial, sumsq_part, temp, attn_out, rinv_k);
  k_m<<<dim3(NB, 24), dim3(256), 0, stream>>>(attn_out, proj_w, rinv_k, Mbf);
  k_final<<<dim3(NN/BN, CC/BM, NB), dim3(256), 0, stream>>>(in2, Mbf, proj_b, out);
}

// Round 13
// 130.247 us; speedup vs baseline: 1.2291x; 1.0965x over previous
//
#include <hip/hip_runtime.h>
#include <hip/hip_bf16.h>

#define NB 4
#define CC 384
#define HEADS 8
#define HD 48
#define NN 16384          // H*W
#define NROWS (NB*CC)     // 1536

typedef __attribute__((ext_vector_type(8))) short bf16x8;
typedef __attribute__((ext_vector_type(4))) float f32x4;

__device__ __forceinline__ unsigned short f2bf(float f) {
  __hip_bfloat16 h = __float2bfloat16(f);
  return __builtin_bit_cast(unsigned short, h);
}
__device__ __forceinline__ unsigned int packbf(float a, float b) {
  return (unsigned int)f2bf(a) | ((unsigned int)f2bf(b) << 16);
}
__device__ __forceinline__ float bf2f(short s) {
  unsigned int u = ((unsigned int)(unsigned short)s) << 16;
  return __builtin_bit_cast(float, u);
}

// ---------------- K2: Gram, LDS-staged coalesced loads + fused sumsq --------
// grid (32 bh, 32 chunks). BK=512 per block in 2 rounds of 256.
// Staging tile [48][264] bf16 per tensor (stride 132 dw = 4 mod 32: frag
// b128 reads at bank floor). red[][] aliased onto staging after last round.
#define SROW 264           // padded row length in bf16
__global__ __launch_bounds__(256) void k_gram(
    const float* __restrict__ in1, const float* __restrict__ in2,
    float* __restrict__ partial, float* __restrict__ sumsq_part)
{
  int bh = blockIdx.x;     // 32
  int chunk = blockIdx.y;  // 32
  int wave = threadIdx.x >> 6, lane = threadIdx.x & 63;
  int b = bh >> 3, h = bh & 7;
  size_t base = ((size_t)(b*CC + h*HD)) * NN;
  int lrow = lane & 15, lkg = lane >> 4;

  __shared__ char smem[50688];
  unsigned short* sq_ = (unsigned short*)smem;            // q tile 25344 B
  unsigned short* sk_ = (unsigned short*)(smem + 25344);  // k tile 25344 B
  float* red = (float*)smem;                 // alias: 4*48*50*4 = 38400 B
  float* sqs = (float*)(smem + 38400);       // alias: 4*96*4 = 1536 B

  f32x4 acc[3][3] = {};
  float ssq[3] = {0.f,0.f,0.f}, ssk[3] = {0.f,0.f,0.f};

  for (int rnd = 0; rnd < 2; ++rnd) {
    int kbase = chunk*512 + rnd*256;
    // stage 96 rows (48 q + 48 k) x 256 floats; wave w -> rows w*24..+23
    // (uniform per wave: w0,w1 = q rows; w2,w3 = k rows)
    #pragma unroll 8
    for (int rr = 0; rr < 24; ++rr) {
      int row = wave*24 + rr;
      int tr = row < 48 ? row : row - 48;
      const float* src = (row < 48 ? in1 : in2) + base + (size_t)tr*NN + kbase;
      float4 v = *(const float4*)(src + lane*4);
      unsigned short* dstp = (row < 48 ? sq_ : sk_) + tr*SROW + lane*4;
      *(unsigned int*)(dstp)     = packbf(v.x, v.y);
      *(unsigned int*)(dstp + 2) = packbf(v.z, v.w);
    }
    __syncthreads();
    // MFMA: wave covers staged cols [wave*64, wave*64+64)
    #pragma unroll
    for (int ks = 0; ks < 2; ++ks) {
      int col = wave*64 + ks*32 + lkg*8;
      bf16x8 a[3], bb[3];
      #pragma unroll
      for (int t = 0; t < 3; ++t) {
        int rr2 = t*16 + lrow;
        a[t]  = *(const bf16x8*)(sq_ + rr2*SROW + col);
        bb[t] = *(const bf16x8*)(sk_ + rr2*SROW + col);
      }
      #pragma unroll
      for (int t = 0; t < 3; ++t)
        #pragma unroll
        for (int j = 0; j < 8; ++j) {
          float fa = bf2f(a[t][j]);  ssq[t] += fa*fa;
          float fb = bf2f(bb[t][j]); ssk[t] += fb*fb;
        }
      #pragma unroll
      for (int i = 0; i < 3; ++i)
        #pragma unroll
        for (int j = 0; j < 3; ++j)
          acc[i][j] = __builtin_amdgcn_mfma_f32_16x16x32_bf16(a[i], bb[j], acc[i][j], 0, 0, 0);
    }
    __syncthreads();   // drain reads before next staging / alias phase
  }

  // alias phase: cross-wave reduce through red[4][48][50]
  #pragma unroll
  for (int i = 0; i < 3; ++i)
    #pragma unroll
    for (int j = 0; j < 3; ++j)
      #pragma unroll
      for (int m = 0; m < 4; ++m) {
        int rr2 = i*16 + (lane>>4)*4 + m;
        int cc2 = j*16 + (lane&15);
        red[(size_t)wave*2400 + rr2*50 + cc2] = acc[i][j][m];
      }
  #pragma unroll
  for (int t = 0; t < 3; ++t) {
    float s = ssq[t]; s += __shfl_xor(s, 16); s += __shfl_xor(s, 32);
    if (lane < 16) sqs[wave*96 + t*16 + lane] = s;
    float s2 = ssk[t]; s2 += __shfl_xor(s2, 16); s2 += __shfl_xor(s2, 32);
    if (lane < 16) sqs[wave*96 + 48 + t*16 + lane] = s2;
  }
  __syncthreads();
  float* pout = partial + ((size_t)bh*32 + chunk) * (HD*HD);
  for (int e = threadIdx.x; e < HD*HD; e += 256) {
    int r = e / HD, c = e % HD;
    pout[e] = red[r*50+c] + red[2400 + r*50+c] + red[4800 + r*50+c] + red[7200 + r*50+c];
  }
  if (threadIdx.x < 96) {
    float* sout = sumsq_part + ((size_t)bh*32 + chunk) * 96;
    sout[threadIdx.x] = sqs[threadIdx.x] + sqs[96 + threadIdx.x]
                      + sqs[192 + threadIdx.x] + sqs[288 + threadIdx.x];
  }
}

// ---------------- K3a: reduce partials+sumsq -> rinv, softmax ---------------
__global__ __launch_bounds__(256) void k_redsm(
    const float* __restrict__ partial, const float* __restrict__ sumsq_part,
    const float* __restrict__ temp, float* __restrict__ attn_out,
    float* __restrict__ rinv_k_g)
{
  int bh = blockIdx.x; int b = bh >> 3, h = bh & 7;
  __shared__ float attn[HD][HD+1];
  __shared__ float rqs[HD], rks[HD];
  if (threadIdx.x < 96) {
    float s = 0.f;
    #pragma unroll
    for (int c = 0; c < 32; ++c)
      s += sumsq_part[((size_t)bh*32 + c)*96 + threadIdx.x];
    float rinv = 1.f / fmaxf(sqrtf(s), 1e-12f);
    if (threadIdx.x < 48) rqs[threadIdx.x] = rinv;
    else { rks[threadIdx.x-48] = rinv; rinv_k_g[b*CC + h*HD + threadIdx.x-48] = rinv; }
  }
  const float* p = partial + (size_t)bh * 32 * (HD*HD);
  float tscale = temp[h];
  __syncthreads();
  for (int e = threadIdx.x; e < HD*HD; e += 256) {
    float s = 0.f;
    #pragma unroll
    for (int c2 = 0; c2 < 32; ++c2) s += p[c2*(HD*HD) + e];
    attn[e/HD][e%HD] = s * tscale * rqs[e/HD] * rks[e%HD];
  }
  __syncthreads();
  if (threadIdx.x < HD) {
    float* rowp = attn[threadIdx.x];
    float m = rowp[0];
    for (int j = 1; j < HD; ++j) m = fmaxf(m, rowp[j]);
    float sum = 0.f;
    for (int j = 0; j < HD; ++j) { float e = expf(rowp[j]-m); rowp[j] = e; sum += e; }
    float inv = 1.f / sum;
    for (int j = 0; j < HD; ++j) rowp[j] *= inv;
  }
  __syncthreads();
  float* ao = attn_out + (size_t)bh * (HD*HD);
  for (int e = threadIdx.x; e < HD*HD; e += 256)
    ao[e] = attn[e/HD][e%HD];
}

// ---------------- K3b: M = (projW_h @ attn_h) * rinv_k[col], bf16 ----------
__global__ __launch_bounds__(256) void k_m(
    const float* __restrict__ attn, const float* __restrict__ proj_w,
    const float* __restrict__ rinv_k, unsigned short* __restrict__ Mbf)
{
  int b = blockIdx.x, ot = blockIdx.y;  // grid (4, 24)
  int o0 = ot * 16;
  __shared__ float sw[16*CC];           // 24.6 KB
  __shared__ float sa[HEADS*HD*HD];     // 73.7 KB
  const float* ab = attn + (size_t)b * HEADS * HD * HD;
  for (int i = threadIdx.x; i < HEADS*HD*HD; i += 256) sa[i] = ab[i];
  for (int i = threadIdx.x; i < 16*CC; i += 256)
    sw[i] = proj_w[(size_t)(o0 + i/CC)*CC + (i%CC)];
  __syncthreads();
  for (int idx = threadIdx.x; idx < 16*96; idx += 256) {
    int o = idx / 96, c4 = idx % 96;
    int col = c4 * 4;
    int h = col / HD, d = col % HD;
    const float* wp = sw + o*CC + h*HD;
    const float* ap = sa + h*HD*HD + d;
    f32x4 s = {0.f, 0.f, 0.f, 0.f};
    #pragma unroll
    for (int c2 = 0; c2 < HD; ++c2) {
      float w = wp[c2];
      f32x4 av = *(const f32x4*)(ap + c2*HD);
      s += w * av;
    }
    f32x4 rk = *(const f32x4*)(rinv_k + b*CC + col);
    s *= rk;
    ushort4 o4;
    o4.x = f2bf(s[0]); o4.y = f2bf(s[1]); o4.z = f2bf(s[2]); o4.w = f2bf(s[3]);
    *(ushort4*)(Mbf + ((size_t)b*CC + o0 + o)*CC + col) = o4;
  }
}

// ---------------- K5: out = M @ bf16(in2) + bias, B staged from fp32 --------
#define BM 128
#define BN 128
#define BK 64

__global__ __launch_bounds__(256) void k_final(
    const float* __restrict__ in2, const unsigned short* __restrict__ Mbf,
    const float* __restrict__ bias, float* __restrict__ out)
{
  int b = blockIdx.z;
  int bm = blockIdx.y * BM, bn = blockIdx.x * BN;
  int tid = threadIdx.x, lane = tid & 63, wave = tid >> 6;
  int wrow = wave >> 1, wcol = wave & 1;
  __shared__ unsigned short Bt[BN * BK];   // transposed+swizzled [n][k], 16 KB
  char* btb = (char*)Bt;
  const float* kb = in2 + (size_t)b * CC * NN;
  const unsigned short* Mb = Mbf + (size_t)b * CC * CC;
  f32x4 acc[4][4] = {};
  int lrow = lane & 15, lkg = lane >> 4;
  for (int k0 = 0; k0 < CC; k0 += BK) {
    #pragma unroll
    for (int s = 0; s < 2; ++s) {
      int slot = tid + s*256;
      int cp = slot >> 4;        // pair of channel rows, 0..31
      int ng = slot & 15;        // group of 8 n-columns
      int n0 = ng * 8;
      int c = k0 + cp*2;
      const float* p0 = kb + (size_t)c*NN + bn + n0;
      const float* p1 = kb + (size_t)(c+1)*NN + bn + n0;
      float4 a0 = *(const float4*)p0, a1 = *((const float4*)p0 + 1);
      float4 b0 = *(const float4*)p1, b1 = *((const float4*)p1 + 1);
      float lo[8] = {a0.x,a0.y,a0.z,a0.w,a1.x,a1.y,a1.z,a1.w};
      float hi[8] = {b0.x,b0.y,b0.z,b0.w,b1.x,b1.y,b1.z,b1.w};
      #pragma unroll
      for (int i = 0; i < 8; ++i) {
        int n = n0 + i;
        unsigned int val = packbf(lo[i], hi[i]);
        int pc = (cp>>2) ^ (n & 7) ^ ((n >> 3) & 7);
        *(unsigned int*)(btb + n*128 + (pc<<4) + ((cp&3)<<2)) = val;
      }
    }
    __syncthreads();
    #pragma unroll
    for (int kk = 0; kk < BK; kk += 32) {
      bf16x8 af[4], bfr[4];
      #pragma unroll
      for (int t = 0; t < 4; ++t) {
        int o = bm + wrow*64 + t*16 + lrow;
        af[t] = *(const bf16x8*)(Mb + (size_t)o*CC + (k0 + kk + (lkg<<3)));
        int n = wcol*64 + t*16 + lrow;
        int lc = (kk>>3) + lkg;
        int pc = lc ^ (n & 7) ^ ((n >> 3) & 7);
        bfr[t] = *(const bf16x8*)(btb + n*128 + (pc<<4));
      }
      #pragma unroll
      for (int i = 0; i < 4; ++i)
        #pragma unroll
        for (int j = 0; j < 4; ++j)
          acc[i][j] = __builtin_amdgcn_mfma_f32_16x16x32_bf16(af[i], bfr[j], acc[i][j], 0, 0, 0);
    }
    __syncthreads();
  }
  #pragma unroll
  for (int i = 0; i < 4; ++i) {
    int obase = bm + wrow*64 + i*16 + lkg*4;
    #pragma unroll
    for (int j = 0; j < 4; ++j) {
      int n = bn + wcol*64 + j*16 + lrow;
      #pragma unroll
      for (int m = 0; m < 4; ++m) {
        int o = obase + m;
        out[((size_t)b*CC + o)*NN + n] = acc[i][j][m] + bias[o];
      }
    }
  }
}

extern "C" void kernel_launch(void* const* d_in, const int* in_sizes, int n_in,
                              void* d_out, int out_size, void* d_ws, size_t ws_size,
                              hipStream_t stream)
{
  const float* in1    = (const float*)d_in[0];
  const float* in2    = (const float*)d_in[1];
  const float* temp   = (const float*)d_in[2];
  const float* proj_w = (const float*)d_in[3];
  const float* proj_b = (const float*)d_in[4];
  float* out = (float*)d_out;
  char* ws = (char*)d_ws;

  size_t off = 0;
  float* partial    = (float*)(ws + off); off += (size_t)32*32*HD*HD*4;           // 9437184
  float* sumsq_part = (float*)(ws + off); off += (size_t)32*32*96*4;              // 393216
  float* attn_out   = (float*)(ws + off); off += (size_t)32*HD*HD*4;              // 294912
  float* rinv_k     = (float*)(ws + off); off += NROWS*4;                         // 6144
  unsigned short* Mbf = (unsigned short*)(ws + off);                              // 1179648

  k_gram<<<dim3(32, 32), dim3(256), 0, stream>>>(in1, in2, partial, sumsq_part);
  k_redsm<<<dim3(32), dim3(256), 0, stream>>>(partial, sumsq_part, temp, attn_out, rinv_k);
  k_m<<<dim3(NB, 24), dim3(256), 0, stream>>>(attn_out, proj_w, rinv_k, Mbf);
  k_final<<<dim3(NN/BN, CC/BM, NB), dim3(256), 0, stream>>>(in2, Mbf, proj_b, out);
}